// Round 7
// baseline (85.379 us; speedup 1.0000x reference)
//
#include <hip/hip_runtime.h>

typedef int   int4v   __attribute__((ext_vector_type(4)));
typedef float float4v __attribute__((ext_vector_type(4)));

#define N_DIM 65536

__device__ __forceinline__ int quant8(float v) {
    int q = (int)rintf(v);           // round-half-to-even, matches jnp.round
    q = q > 127 ? 127 : q;
    q = q < -128 ? -128 : q;
    return q;
}

__device__ __forceinline__ int clamp16(int s) {
    s = s > 32767 ? 32767 : s;
    s = s < -32768 ? -32768 : s;
    return s;
}

__device__ __forceinline__ unsigned int qpack(float4v v) {
    int q0 = quant8(v.x * 16.0f);
    int q1 = quant8(v.y * 16.0f);
    int q2 = quant8(v.z * 16.0f);
    int q3 = quant8(v.w * 16.0f);
    return (unsigned int)((q0 & 0xff) | ((q1 & 0xff) << 8) |
                          ((q2 & 0xff) << 16) | ((q3 & 0xff) << 24));
}

// Pre-pass: w1/w2 are int-valued float32 in [-16,15]; pack to int8.
__global__ __launch_bounds__(256) void quant_weights(const float* __restrict__ w1,
                                                     const float* __restrict__ w2,
                                                     unsigned char* __restrict__ w1q,
                                                     unsigned char* __restrict__ w2q) {
    int idx = blockIdx.x * 256 + threadIdx.x;   // 32768 threads, 4 elems each
    const float* src;
    unsigned char* dst;
    int off;
    if (idx < 16384) { src = w1; dst = w1q; off = idx * 4; }
    else             { src = w2; dst = w2q; off = (idx - 16384) * 4; }
    float4v f = *reinterpret_cast<const float4v*>(src + off);
    unsigned int dw = (unsigned int)(((int)f.x & 0xff) | (((int)f.y & 0xff) << 8) |
                                     (((int)f.z & 0xff) << 16) | (((int)f.w & 0xff) << 24));
    *reinterpret_cast<unsigned int*>(dst + off) = dw;
}

// Fused kernel: 4 independent waves/block (no barriers, wave-private LDS).
// Each wave processes TWO 16-column strips, software-pipelined: strip s+1's
// x-loads are issued mid-compute of strip s so the strip never stalls on HBM.
__global__ __launch_bounds__(256, 2) void qdq_main(const float* __restrict__ x,
                                                   const unsigned char* __restrict__ w1q,
                                                   const unsigned char* __restrict__ w2q,
                                                   int* __restrict__ out) {
    __shared__ unsigned char xq[4][4096];   // per-wave [16 n][256 d] bytes, swizzled;
                                            // reused for the prob tile

    const int tid  = threadIdx.x;
    const int wv   = tid >> 6;
    const int lane = tid & 63;
    const int c    = lane & 15;    // MFMA col-in-tile / A row-in-rowtile
    const int g    = lane >> 4;    // MFMA k-group 0..3
    const int r16  = lane >> 2;    // load phase: row within 16-row chunk
    const int cq   = lane & 3;     // load phase: float4 column group
    unsigned char* xb = xq[wv];

    // Transpose constants (verified 4x4 byte transpose; partners lane^4, lane^8)
    const int R = r16 & 3;
    const unsigned int sel1 = (R & 1) ? 0x03070206u : 0x05010400u;
    const unsigned int sel2 = (R & 2) ? 0x07060302u : 0x01000504u;
    const int colsel = (0x3120 >> (R * 4)) & 0xF;   // {0,2,1,3}[R]
    const int n_t = cq * 4 + colsel;                // strip-local col 0..15
    const int qb  = r16 & 12;                       // d-quad base within 16-row chunk

    const int colw = blockIdx.x * 128 + wv * 16;    // strip s: col0 = colw + s*64

    // ---- Prologue: issue strip-0 x loads (16 float4/lane, 64B segments) ----
    float4v raw1[8], raw2[8];
    {
        const float* xp = x + (size_t)r16 * N_DIM + colw + cq * 4;
        #pragma unroll
        for (int i = 0; i < 8; ++i)
            raw1[i] = *reinterpret_cast<const float4v*>(xp + (size_t)i * (16 * N_DIM));
        #pragma unroll
        for (int i = 0; i < 8; ++i)
            raw2[i] = *reinterpret_cast<const float4v*>(xp + (size_t)(8 + i) * (16 * N_DIM));
    }

    #pragma unroll
    for (int s = 0; s < 2; ++s) {
        const int col0 = colw + s * 64;

        // ---- 1. Quantize + pack the held raw tile ----
        unsigned int W[16];
        #pragma unroll
        for (int i = 0; i < 8; ++i) W[i] = qpack(raw1[i]);
        #pragma unroll
        for (int i = 0; i < 8; ++i) W[8 + i] = qpack(raw2[i]);

        // ---- 2. 4x4 byte transpose + swizzled LDS write ----
        #pragma unroll
        for (int i = 0; i < 16; ++i) {
            unsigned int t = (unsigned int)__shfl_xor((int)W[i], 4);
            unsigned int Q = __builtin_amdgcn_perm(t, W[i], sel1);
            unsigned int u = (unsigned int)__shfl_xor((int)Q, 8);
            unsigned int F = __builtin_amdgcn_perm(Q, u, sel2);
            *reinterpret_cast<unsigned int*>(
                xb + n_t * 256 + ((i * 16 + qb) ^ (n_t << 4))) = F;
        }

        // ---- 3. B-fragments for GEMM1 ----
        int4v bq[4];
        #pragma unroll
        for (int kk = 0; kk < 4; ++kk)
            bq[kk] = *reinterpret_cast<const int4v*>(
                xb + c * 256 + ((kk * 64 + g * 16) ^ (c << 4)));

        // ---- Pipeline: issue next strip's first 8 loads (rows 0..127) ----
        if (s == 0) {
            const float* xp = x + (size_t)r16 * N_DIM + (colw + 64) + cq * 4;
            #pragma unroll
            for (int i = 0; i < 8; ++i)
                raw1[i] = *reinterpret_cast<const float4v*>(xp + (size_t)i * (16 * N_DIM));
        }

        // ---- 4. GEMM1: 16 row-tiles, A prefetch 1 ahead ----
        const unsigned char* a1 = w1q + c * 256 + g * 16;
        unsigned int sc[32];
        int im = -(1 << 30);
        int4v a_cur[4];
        #pragma unroll
        for (int kk = 0; kk < 4; ++kk)
            a_cur[kk] = *reinterpret_cast<const int4v*>(a1 + kk * 64);
        #pragma unroll
        for (int rt = 0; rt < 16; ++rt) {
            int4v a_nxt[4];
            if (rt < 15) {
                #pragma unroll
                for (int kk = 0; kk < 4; ++kk)
                    a_nxt[kk] = *reinterpret_cast<const int4v*>(
                        a1 + (rt + 1) * 4096 + kk * 64);
            }
            int4v acc = {0, 0, 0, 0};
            #pragma unroll
            for (int kk = 0; kk < 4; ++kk)
                acc = __builtin_amdgcn_mfma_i32_16x16x64_i8(a_cur[kk], bq[kk], acc, 0, 0, 0);
            const int s0 = clamp16(acc[0]), s1 = clamp16(acc[1]);
            const int s2 = clamp16(acc[2]), s3 = clamp16(acc[3]);
            int m01 = s0 > s1 ? s0 : s1, m23 = s2 > s3 ? s2 : s3;
            int m = m01 > m23 ? m01 : m23;
            im = im > m ? im : m;
            sc[2 * rt]     = (unsigned int)((s0 & 0xffff) | (s1 << 16));
            sc[2 * rt + 1] = (unsigned int)((s2 & 0xffff) | (s3 << 16));
            #pragma unroll
            for (int kk = 0; kk < 4; ++kk) a_cur[kk] = a_nxt[kk];
        }

        // ---- Pipeline: issue next strip's last 8 loads (rows 128..255) ----
        if (s == 0) {
            const float* xp = x + (size_t)r16 * N_DIM + (colw + 64) + cq * 4;
            #pragma unroll
            for (int i = 0; i < 8; ++i)
                raw2[i] = *reinterpret_cast<const float4v*>(
                    xp + (size_t)(8 + i) * (16 * N_DIM));
        }

        // ---- 5. Softmax over k (column lives in lanes c, c+16, c+32, c+48) ----
        {
            int o = __shfl_xor(im, 16); im = im > o ? im : o;
            o = __shfl_xor(im, 32);     im = im > o ? im : o;
        }
        const float C = 0.0056355275034725134f;   // SCORE_SCALE * log2(e)
        float sum = 0.0f;
        #pragma unroll
        for (int i = 0; i < 32; ++i) {
            sum += exp2f((float)((int)(short)(sc[i] & 0xffffu) - im) * C);
            sum += exp2f((float)(((int)sc[i] >> 16) - im) * C);
        }
        sum += __shfl_xor(sum, 16);
        sum += __shfl_xor(sum, 32);
        const float qs = 2048.0f / sum;   // (1/PROB_SCALE) / sum

        // ---- 6. Quantize probs (recompute exp2) into the REUSED xb tile ----
        #pragma unroll
        for (int rt = 0; rt < 16; ++rt) {
            const unsigned int w0 = sc[2 * rt];
            const unsigned int w1 = sc[2 * rt + 1];
            int q0 = (int)rintf(exp2f((float)((int)(short)(w0 & 0xffffu) - im) * C) * qs);
            int q1 = (int)rintf(exp2f((float)(((int)w0 >> 16) - im) * C) * qs);
            int q2 = (int)rintf(exp2f((float)((int)(short)(w1 & 0xffffu) - im) * C) * qs);
            int q3 = (int)rintf(exp2f((float)(((int)w1 >> 16) - im) * C) * qs);
            q0 = q0 > 127 ? 127 : q0;
            q1 = q1 > 127 ? 127 : q1;
            q2 = q2 > 127 ? 127 : q2;
            q3 = q3 > 127 ? 127 : q3;
            *reinterpret_cast<unsigned int*>(
                xb + c * 256 + ((rt * 16 + g * 4) ^ (c << 4))) =
                (unsigned int)(q0 | (q1 << 8) | (q2 << 16) | (q3 << 24));
        }

        // ---- 7. GEMM2: B-frags from prob tile; A prefetch; direct stores ----
        int4v b2[4];
        #pragma unroll
        for (int kk = 0; kk < 4; ++kk)
            b2[kk] = *reinterpret_cast<const int4v*>(
                xb + c * 256 + ((kk * 64 + g * 16) ^ (c << 4)));

        const unsigned char* a2 = w2q + c * 256 + g * 16;
        #pragma unroll
        for (int kk = 0; kk < 4; ++kk)
            a_cur[kk] = *reinterpret_cast<const int4v*>(a2 + kk * 64);
        #pragma unroll
        for (int rt = 0; rt < 16; ++rt) {
            int4v a_nxt[4];
            if (rt < 15) {
                #pragma unroll
                for (int kk = 0; kk < 4; ++kk)
                    a_nxt[kk] = *reinterpret_cast<const int4v*>(
                        a2 + (rt + 1) * 4096 + kk * 64);
            }
            int4v acc = {0, 0, 0, 0};
            #pragma unroll
            for (int kk = 0; kk < 4; ++kk)
                acc = __builtin_amdgcn_mfma_i32_16x16x64_i8(a_cur[kk], b2[kk], acc, 0, 0, 0);
            #pragma unroll
            for (int r = 0; r < 4; ++r) {
                out[(size_t)(rt * 16 + g * 4 + r) * N_DIM + col0 + c] = clamp16(acc[r]);
            }
            #pragma unroll
            for (int kk = 0; kk < 4; ++kk) a_cur[kk] = a_nxt[kk];
        }
    }
}

extern "C" void kernel_launch(void* const* d_in, const int* in_sizes, int n_in,
                              void* d_out, int out_size, void* d_ws, size_t ws_size,
                              hipStream_t stream) {
    const float* x  = (const float*)d_in[0];
    const float* w1 = (const float*)d_in[1];
    const float* w2 = (const float*)d_in[2];
    int* out = (int*)d_out;

    unsigned char* w1q = (unsigned char*)d_ws;
    unsigned char* w2q = w1q + 65536;

    quant_weights<<<128, 256, 0, stream>>>(w1, w2, w1q, w2q);
    qdq_main<<<512, 256, 0, stream>>>(x, w1q, w2q, out);
}

// Round 8
// 62.303 us; speedup vs baseline: 1.3704x; 1.3704x over previous
//
#include <hip/hip_runtime.h>

typedef int   int4v   __attribute__((ext_vector_type(4)));
typedef float float4v __attribute__((ext_vector_type(4)));

#define N_DIM 65536

__device__ __forceinline__ int quant8(float v) {
    int q = (int)rintf(v);           // round-half-to-even, matches jnp.round
    q = q > 127 ? 127 : q;
    q = q < -128 ? -128 : q;
    return q;
}

__device__ __forceinline__ int clamp16(int s) {
    s = s > 32767 ? 32767 : s;
    s = s < -32768 ? -32768 : s;
    return s;
}

__device__ __forceinline__ unsigned int qpack(float4v v) {
    int q0 = quant8(v.x * 16.0f);
    int q1 = quant8(v.y * 16.0f);
    int q2 = quant8(v.z * 16.0f);
    int q3 = quant8(v.w * 16.0f);
    return (unsigned int)((q0 & 0xff) | ((q1 & 0xff) << 8) |
                          ((q2 & 0xff) << 16) | ((q3 & 0xff) << 24));
}

// Raw v_exp_f32 (2^x). Args here are always <= 0; denormal range flushes to 0
// on both sides of the comparison, and 1-ULP accuracy is far inside threshold.
__device__ __forceinline__ float fexp2(float a) {
    float r;
    asm("v_exp_f32 %0, %1" : "=v"(r) : "v"(a));
    return r;
}

// Pre-pass: w1/w2 are int-valued float32 in [-16,15]; pack to int8.
__global__ __launch_bounds__(256) void quant_weights(const float* __restrict__ w1,
                                                     const float* __restrict__ w2,
                                                     unsigned char* __restrict__ w1q,
                                                     unsigned char* __restrict__ w2q) {
    int idx = blockIdx.x * 256 + threadIdx.x;   // 32768 threads, 4 elems each
    const float* src;
    unsigned char* dst;
    int off;
    if (idx < 16384) { src = w1; dst = w1q; off = idx * 4; }
    else             { src = w2; dst = w2q; off = (idx - 16384) * 4; }
    float4v f = *reinterpret_cast<const float4v*>(src + off);
    unsigned int dw = (unsigned int)(((int)f.x & 0xff) | (((int)f.y & 0xff) << 8) |
                                     (((int)f.z & 0xff) << 16) | (((int)f.w & 0xff) << 24));
    *reinterpret_cast<unsigned int*>(dst + off) = dw;
}

// Fused kernel: 4 independent waves/block, each owns a 32-column strip
// end-to-end. No barriers, wave-private LDS (reused xq -> probs).
// Deep ILP: 3-group modulo pipeline on weight fragments in both GEMMs.
__global__ __launch_bounds__(256) void qdq_main(const float* __restrict__ x,
                                                const unsigned char* __restrict__ w1q,
                                                const unsigned char* __restrict__ w2q,
                                                int* __restrict__ out) {
    __shared__ unsigned char xq[4][8192];   // per-wave [32 n][256 d] bytes, swizzled

    const int tid  = threadIdx.x;
    const int wv   = tid >> 6;
    const int lane = tid & 63;
    const int c    = lane & 15;     // MFMA col-in-tile / A row-in-rowtile
    const int g    = lane >> 4;     // MFMA k-group 0..3
    const int colbase = blockIdx.x * 128 + wv * 32;
    unsigned char* xb = xq[wv];

    // ---- 1. Issue ALL x loads (32 float4/lane; 8 rows x 128B segments/instr) ----
    const int rsub = lane >> 3;     // 0..7
    const int cg   = lane & 7;      // float4 group
    float4v raw[32];
    {
        const float* xp = x + (size_t)rsub * N_DIM + colbase + cg * 4;
        #pragma unroll
        for (int i = 0; i < 32; ++i)
            raw[i] = *reinterpret_cast<const float4v*>(xp + (size_t)i * (8 * N_DIM));
    }
    unsigned int W[32];
    #pragma unroll
    for (int i = 0; i < 32; ++i) W[i] = qpack(raw[i]);

    // ---- 2. Hoist GEMM1's 3 prologue A-groups (L2 latency under transpose) ----
    const unsigned char* a1 = w1q + c * 256 + g * 16;
    int4v apf[3][8];
    #pragma unroll
    for (int p = 0; p < 3; ++p)
        #pragma unroll
        for (int j = 0; j < 8; ++j)
            apf[p][j] = *reinterpret_cast<const int4v*>(
                a1 + (p * 2 + (j >> 2)) * 4096 + (j & 3) * 64);

    // ---- 3. In-register 4x4 byte transpose (partners lane^8, lane^16) ----
    const int R = rsub & 3;
    const unsigned int sel1 = (R & 1) ? 0x03070206u : 0x05010400u;
    const unsigned int sel2 = (R & 2) ? 0x07060302u : 0x01000504u;
    const int colsel = (0x3120 >> (R * 4)) & 0xF;   // {0,2,1,3}[R]
    const int n_t = cg * 4 + colsel;                // strip-local col 0..31
    const int qb  = rsub & 4;
    #pragma unroll
    for (int i = 0; i < 32; ++i) {
        unsigned int t = (unsigned int)__shfl_xor((int)W[i], 8);
        unsigned int Q = __builtin_amdgcn_perm(t, W[i], sel1);
        unsigned int u = (unsigned int)__shfl_xor((int)Q, 16);
        unsigned int F = __builtin_amdgcn_perm(Q, u, sel2);
        const int dbase = i * 8 + qb;
        *reinterpret_cast<unsigned int*>(
            xb + n_t * 256 + (dbase ^ ((n_t & 15) << 4))) = F;
    }

    // ---- 4. B-fragments for GEMM1 (2 tiles x 4 k-chunks) ----
    int4v bq[2][4];
    #pragma unroll
    for (int t = 0; t < 2; ++t)
        #pragma unroll
        for (int kk = 0; kk < 4; ++kk)
            bq[t][kk] = *reinterpret_cast<const int4v*>(
                xb + (t * 16 + c) * 256 + ((kk * 64 + g * 16) ^ (c << 4)));

    // ---- 5. GEMM1: 8 groups of 2 row-tiles, 3-deep load pipeline ----
    unsigned int scA[32], scB[32];
    int imA = -(1 << 30), imB = -(1 << 30);
    #pragma unroll
    for (int grp = 0; grp < 8; ++grp) {
        const int b = grp % 3;
        #pragma unroll
        for (int l = 0; l < 2; ++l) {
            const int rt = grp * 2 + l;
            int4v accA = {0, 0, 0, 0}, accB = {0, 0, 0, 0};
            #pragma unroll
            for (int kk = 0; kk < 4; ++kk) {
                accA = __builtin_amdgcn_mfma_i32_16x16x64_i8(apf[b][l * 4 + kk], bq[0][kk], accA, 0, 0, 0);
                accB = __builtin_amdgcn_mfma_i32_16x16x64_i8(apf[b][l * 4 + kk], bq[1][kk], accB, 0, 0, 0);
            }
            {
                const int s0 = clamp16(accA[0]), s1 = clamp16(accA[1]);
                const int s2 = clamp16(accA[2]), s3 = clamp16(accA[3]);
                int m01 = s0 > s1 ? s0 : s1, m23 = s2 > s3 ? s2 : s3;
                int m = m01 > m23 ? m01 : m23;
                imA = imA > m ? imA : m;
                scA[2 * rt]     = (unsigned int)((s0 & 0xffff) | (s1 << 16));
                scA[2 * rt + 1] = (unsigned int)((s2 & 0xffff) | (s3 << 16));
            }
            {
                const int s0 = clamp16(accB[0]), s1 = clamp16(accB[1]);
                const int s2 = clamp16(accB[2]), s3 = clamp16(accB[3]);
                int m01 = s0 > s1 ? s0 : s1, m23 = s2 > s3 ? s2 : s3;
                int m = m01 > m23 ? m01 : m23;
                imB = imB > m ? imB : m;
                scB[2 * rt]     = (unsigned int)((s0 & 0xffff) | (s1 << 16));
                scB[2 * rt + 1] = (unsigned int)((s2 & 0xffff) | (s3 << 16));
            }
        }
        if (grp < 5) {   // refill this buffer with group grp+3
            #pragma unroll
            for (int j = 0; j < 8; ++j)
                apf[b][j] = *reinterpret_cast<const int4v*>(
                    a1 + ((grp + 3) * 2 + (j >> 2)) * 4096 + (j & 3) * 64);
        }
    }

    // ---- 6. Softmax per tile (int max; raw v_exp_f32) ----
    {
        int o = __shfl_xor(imA, 16); imA = imA > o ? imA : o;
        o = __shfl_xor(imA, 32);     imA = imA > o ? imA : o;
        o = __shfl_xor(imB, 16);     imB = imB > o ? imB : o;
        o = __shfl_xor(imB, 32);     imB = imB > o ? imB : o;
    }
    const float C = 0.0056355275034725134f;   // SCORE_SCALE * log2(e)
    float sumA = 0.0f, sumB = 0.0f;
    #pragma unroll
    for (int i = 0; i < 32; ++i) {
        sumA += fexp2((float)((int)(short)(scA[i] & 0xffffu) - imA) * C);
        sumA += fexp2((float)(((int)scA[i] >> 16) - imA) * C);
        sumB += fexp2((float)((int)(short)(scB[i] & 0xffffu) - imB) * C);
        sumB += fexp2((float)(((int)scB[i] >> 16) - imB) * C);
    }
    sumA += __shfl_xor(sumA, 16); sumA += __shfl_xor(sumA, 32);
    sumB += __shfl_xor(sumB, 16); sumB += __shfl_xor(sumB, 32);
    const float qsA = 2048.0f / sumA;
    const float qsB = 2048.0f / sumB;

    // ---- 7. Hoist GEMM2's 3 prologue A-groups (latency under exp2 phase) ----
    const unsigned char* a2 = w2q + c * 256 + g * 16;
    int4v apf2[3][8];
    #pragma unroll
    for (int p = 0; p < 3; ++p)
        #pragma unroll
        for (int j = 0; j < 8; ++j)
            apf2[p][j] = *reinterpret_cast<const int4v*>(
                a2 + (p * 2 + (j >> 2)) * 4096 + (j & 3) * 64);

    // ---- 8. Quantize probs (recompute exp2) into the REUSED xb tile ----
    #pragma unroll
    for (int rt = 0; rt < 16; ++rt) {
        #pragma unroll
        for (int t = 0; t < 2; ++t) {
            const unsigned int w0 = t ? scB[2 * rt] : scA[2 * rt];
            const unsigned int w1 = t ? scB[2 * rt + 1] : scA[2 * rt + 1];
            const int im = t ? imB : imA;
            const float qs = t ? qsB : qsA;
            int q0 = (int)rintf(fexp2((float)((int)(short)(w0 & 0xffffu) - im) * C) * qs);
            int q1 = (int)rintf(fexp2((float)(((int)w0 >> 16) - im) * C) * qs);
            int q2 = (int)rintf(fexp2((float)((int)(short)(w1 & 0xffffu) - im) * C) * qs);
            int q3 = (int)rintf(fexp2((float)(((int)w1 >> 16) - im) * C) * qs);
            q0 = q0 > 127 ? 127 : q0;
            q1 = q1 > 127 ? 127 : q1;
            q2 = q2 > 127 ? 127 : q2;
            q3 = q3 > 127 ? 127 : q3;
            *reinterpret_cast<unsigned int*>(
                xb + (t * 16 + c) * 256 + ((rt * 16 + g * 4) ^ (c << 4))) =
                (unsigned int)(q0 | (q1 << 8) | (q2 << 16) | (q3 << 24));
        }
    }

    // ---- 9. B-fragments for GEMM2 ----
    int4v b2[2][4];
    #pragma unroll
    for (int t = 0; t < 2; ++t)
        #pragma unroll
        for (int kk = 0; kk < 4; ++kk)
            b2[t][kk] = *reinterpret_cast<const int4v*>(
                xb + (t * 16 + c) * 256 + ((kk * 64 + g * 16) ^ (c << 4)));

    // ---- 10. GEMM2: same 3-deep pipeline; nontemporal stores ----
    #pragma unroll
    for (int grp = 0; grp < 8; ++grp) {
        const int b = grp % 3;
        #pragma unroll
        for (int l = 0; l < 2; ++l) {
            const int rt = grp * 2 + l;
            int4v accA = {0, 0, 0, 0}, accB = {0, 0, 0, 0};
            #pragma unroll
            for (int kk = 0; kk < 4; ++kk) {
                accA = __builtin_amdgcn_mfma_i32_16x16x64_i8(apf2[b][l * 4 + kk], b2[0][kk], accA, 0, 0, 0);
                accB = __builtin_amdgcn_mfma_i32_16x16x64_i8(apf2[b][l * 4 + kk], b2[1][kk], accB, 0, 0, 0);
            }
            #pragma unroll
            for (int r = 0; r < 4; ++r) {
                const size_t rowoff = (size_t)(rt * 16 + g * 4 + r) * N_DIM + colbase;
                __builtin_nontemporal_store(clamp16(accA[r]), &out[rowoff + c]);
                __builtin_nontemporal_store(clamp16(accB[r]), &out[rowoff + 16 + c]);
            }
        }
        if (grp < 5) {
            #pragma unroll
            for (int j = 0; j < 8; ++j)
                apf2[b][j] = *reinterpret_cast<const int4v*>(
                    a2 + ((grp + 3) * 2 + (j >> 2)) * 4096 + (j & 3) * 64);
        }
    }
}

extern "C" void kernel_launch(void* const* d_in, const int* in_sizes, int n_in,
                              void* d_out, int out_size, void* d_ws, size_t ws_size,
                              hipStream_t stream) {
    const float* x  = (const float*)d_in[0];
    const float* w1 = (const float*)d_in[1];
    const float* w2 = (const float*)d_in[2];
    int* out = (int*)d_out;

    unsigned char* w1q = (unsigned char*)d_ws;
    unsigned char* w2q = w1q + 65536;

    quant_weights<<<128, 256, 0, stream>>>(w1, w2, w1q, w2q);
    qdq_main<<<512, 256, 0, stream>>>(x, w1q, w2q, out);
}

// Round 9
// 42.430 us; speedup vs baseline: 2.0122x; 1.4684x over previous
//
#include <hip/hip_runtime.h>

typedef int   int4v   __attribute__((ext_vector_type(4)));
typedef float float4v __attribute__((ext_vector_type(4)));

#define N_DIM 65536

__device__ __forceinline__ int quant8(float v) {
    int q = (int)rintf(v);           // round-half-to-even, matches jnp.round
    q = q > 127 ? 127 : q;
    q = q < -128 ? -128 : q;
    return q;
}

__device__ __forceinline__ int clamp16(int s) {
    s = s > 32767 ? 32767 : s;
    s = s < -32768 ? -32768 : s;
    return s;
}

__device__ __forceinline__ unsigned int qpack(float4v v) {
    int q0 = quant8(v.x * 16.0f);
    int q1 = quant8(v.y * 16.0f);
    int q2 = quant8(v.z * 16.0f);
    int q3 = quant8(v.w * 16.0f);
    return (unsigned int)((q0 & 0xff) | ((q1 & 0xff) << 8) |
                          ((q2 & 0xff) << 16) | ((q3 & 0xff) << 24));
}

// Raw v_exp_f32 (2^x). Args <= 0; deep-negative underflows to 0 on both sides.
__device__ __forceinline__ float fexp2(float a) {
    float r;
    asm("v_exp_f32 %0, %1" : "=v"(r) : "v"(a));
    return r;
}

// Pre-pass: w1/w2 are int-valued float32 in [-16,15]; pack to int8.
__global__ __launch_bounds__(256) void quant_weights(const float* __restrict__ w1,
                                                     const float* __restrict__ w2,
                                                     unsigned char* __restrict__ w1q,
                                                     unsigned char* __restrict__ w2q) {
    int idx = blockIdx.x * 256 + threadIdx.x;   // 32768 threads, 4 elems each
    const float* src;
    unsigned char* dst;
    int off;
    if (idx < 16384) { src = w1; dst = w1q; off = idx * 4; }
    else             { src = w2; dst = w2q; off = (idx - 16384) * 4; }
    float4v f = *reinterpret_cast<const float4v*>(src + off);
    unsigned int dw = (unsigned int)(((int)f.x & 0xff) | (((int)f.y & 0xff) << 8) |
                                     (((int)f.z & 0xff) << 16) | (((int)f.w & 0xff) << 24));
    *reinterpret_cast<unsigned int*>(dst + off) = dw;
}

// Fused kernel: 8 waves/block. Wave w owns rows [w*32, w*32+32) of both GEMMs
// for ALL strips -> its w1/w2 fragments live in registers for the whole kernel.
// Block processes 8 strips of 32 columns; x prefetched one strip ahead.
__global__ __launch_bounds__(512, 3) void qdq_main(const float* __restrict__ x,
                                                   const unsigned char* __restrict__ w1q,
                                                   const unsigned char* __restrict__ w2q,
                                                   int* __restrict__ out) {
    __shared__ unsigned char xq[8192];   // [32 n][256 d] bytes, swizzled
    __shared__ unsigned char pq[8192];   // [32 n][256 k] bytes, swizzled
    __shared__ int   mb[8][32];          // cross-wave max exchange
    __shared__ float sb[8][32];          // cross-wave sum exchange

    const int tid  = threadIdx.x;
    const int wv   = tid >> 6;      // 0..7
    const int lane = tid & 63;
    const int c    = lane & 15;     // MFMA col-in-tile / A row-in-rowtile
    const int g    = lane >> 4;     // MFMA k-group 0..3

    // x-load / transpose roles: 8 rows x 32 cols (128B segments) per instr
    const int rsub = lane >> 3;     // 0..7
    const int cg   = lane & 7;      // float4 column group
    const int R    = rsub & 3;
    const unsigned int sel1 = (R & 1) ? 0x03070206u : 0x05010400u;
    const unsigned int sel2 = (R & 2) ? 0x07060302u : 0x01000504u;
    const int colsel = (0x3120 >> (R * 4)) & 0xF;   // {0,2,1,3}[R]
    const int n_t = cg * 4 + colsel;                // strip-local col 0..31
    const int qb  = rsub & 4;

    // ---- Persistent A-fragments: rows wv*32 + rt*16 + c, loaded ONCE ----
    int4v a1f[2][4], a2f[2][4];
    {
        const unsigned char* a1 = w1q + (size_t)(wv * 32 + c) * 256 + g * 16;
        const unsigned char* a2 = w2q + (size_t)(wv * 32 + c) * 256 + g * 16;
        #pragma unroll
        for (int rt = 0; rt < 2; ++rt)
            #pragma unroll
            for (int kk = 0; kk < 4; ++kk) {
                a1f[rt][kk] = *reinterpret_cast<const int4v*>(a1 + rt * 4096 + kk * 64);
                a2f[rt][kk] = *reinterpret_cast<const int4v*>(a2 + rt * 4096 + kk * 64);
            }
    }

    const int colstart = blockIdx.x * 256;
    const float* xpb = x + (size_t)(wv * 32 + rsub) * N_DIM + cg * 4;

    // ---- Prologue: strip-0 x loads (wave's rows wv*32 + i*8 + rsub) ----
    float4v raw[4];
    #pragma unroll
    for (int i = 0; i < 4; ++i)
        raw[i] = *reinterpret_cast<const float4v*>(xpb + (size_t)i * (8 * N_DIM) + colstart);

    const float C = 0.0056355275034725134f;   // SCORE_SCALE * log2(e)

    for (int it = 0; it < 8; ++it) {
        const int col0 = colstart + it * 32;

        // ---- 1. Quantize held x; issue next strip's loads ----
        unsigned int Wq[4];
        #pragma unroll
        for (int i = 0; i < 4; ++i) Wq[i] = qpack(raw[i]);
        if (it < 7) {
            #pragma unroll
            for (int i = 0; i < 4; ++i)
                raw[i] = *reinterpret_cast<const float4v*>(
                    xpb + (size_t)i * (8 * N_DIM) + (col0 + 32));
        }

        // ---- 2. 4x4 byte transpose (partners lane^8, lane^16) -> xq ----
        #pragma unroll
        for (int i = 0; i < 4; ++i) {
            unsigned int t = (unsigned int)__shfl_xor((int)Wq[i], 8);
            unsigned int Q = __builtin_amdgcn_perm(t, Wq[i], sel1);
            unsigned int u = (unsigned int)__shfl_xor((int)Q, 16);
            unsigned int F = __builtin_amdgcn_perm(Q, u, sel2);
            const int dbase = wv * 32 + i * 8 + qb;
            *reinterpret_cast<unsigned int*>(
                xq + n_t * 256 + (dbase ^ ((n_t & 15) << 4))) = F;
        }
        __syncthreads();   // T: xq complete

        // ---- 3. B-fragments for GEMM1 (shared by all waves) ----
        int4v bq[2][4];
        #pragma unroll
        for (int t2 = 0; t2 < 2; ++t2)
            #pragma unroll
            for (int kk = 0; kk < 4; ++kk)
                bq[t2][kk] = *reinterpret_cast<const int4v*>(
                    xq + (t2 * 16 + c) * 256 + ((kk * 64 + g * 16) ^ (c << 4)));

        // ---- 4. GEMM1: 2 row-tiles x 2 col-tiles, A resident ----
        unsigned int scA[4], scB[4];
        int imA = -(1 << 30), imB = -(1 << 30);
        #pragma unroll
        for (int rt = 0; rt < 2; ++rt) {
            int4v accA = {0, 0, 0, 0}, accB = {0, 0, 0, 0};
            #pragma unroll
            for (int kk = 0; kk < 4; ++kk) {
                accA = __builtin_amdgcn_mfma_i32_16x16x64_i8(a1f[rt][kk], bq[0][kk], accA, 0, 0, 0);
                accB = __builtin_amdgcn_mfma_i32_16x16x64_i8(a1f[rt][kk], bq[1][kk], accB, 0, 0, 0);
            }
            {
                const int s0 = clamp16(accA[0]), s1 = clamp16(accA[1]);
                const int s2 = clamp16(accA[2]), s3 = clamp16(accA[3]);
                int m01 = s0 > s1 ? s0 : s1, m23 = s2 > s3 ? s2 : s3;
                int m = m01 > m23 ? m01 : m23;
                imA = imA > m ? imA : m;
                scA[2 * rt]     = (unsigned int)((s0 & 0xffff) | (s1 << 16));
                scA[2 * rt + 1] = (unsigned int)((s2 & 0xffff) | (s3 << 16));
            }
            {
                const int s0 = clamp16(accB[0]), s1 = clamp16(accB[1]);
                const int s2 = clamp16(accB[2]), s3 = clamp16(accB[3]);
                int m01 = s0 > s1 ? s0 : s1, m23 = s2 > s3 ? s2 : s3;
                int m = m01 > m23 ? m01 : m23;
                imB = imB > m ? imB : m;
                scB[2 * rt]     = (unsigned int)((s0 & 0xffff) | (s1 << 16));
                scB[2 * rt + 1] = (unsigned int)((s2 & 0xffff) | (s3 << 16));
            }
        }

        // ---- 5. Softmax max: intra-wave then cross-wave ----
        {
            int o = __shfl_xor(imA, 16); imA = imA > o ? imA : o;
            o = __shfl_xor(imA, 32);     imA = imA > o ? imA : o;
            o = __shfl_xor(imB, 16);     imB = imB > o ? imB : o;
            o = __shfl_xor(imB, 32);     imB = imB > o ? imB : o;
        }
        if (g == 0) mb[wv][c] = imA;
        else if (g == 1) mb[wv][16 + c] = imB;
        __syncthreads();   // M
        int gmA = mb[0][c], gmB = mb[0][16 + c];
        #pragma unroll
        for (int j = 1; j < 8; ++j) {
            int a = mb[j][c], b = mb[j][16 + c];
            gmA = gmA > a ? gmA : a;
            gmB = gmB > b ? gmB : b;
        }

        // ---- 6. Softmax sum: intra-wave then cross-wave ----
        float sA = 0.0f, sB = 0.0f;
        #pragma unroll
        for (int i = 0; i < 4; ++i) {
            sA += fexp2((float)((int)(short)(scA[i] & 0xffffu) - gmA) * C);
            sA += fexp2((float)(((int)scA[i] >> 16) - gmA) * C);
            sB += fexp2((float)((int)(short)(scB[i] & 0xffffu) - gmB) * C);
            sB += fexp2((float)(((int)scB[i] >> 16) - gmB) * C);
        }
        sA += __shfl_xor(sA, 16); sA += __shfl_xor(sA, 32);
        sB += __shfl_xor(sB, 16); sB += __shfl_xor(sB, 32);
        if (g == 0) sb[wv][c] = sA;
        else if (g == 1) sb[wv][16 + c] = sB;
        __syncthreads();   // S
        float gsA = 0.0f, gsB = 0.0f;
        #pragma unroll
        for (int j = 0; j < 8; ++j) { gsA += sb[j][c]; gsB += sb[j][16 + c]; }
        const float qsA = 2048.0f / gsA;
        const float qsB = 2048.0f / gsB;

        // ---- 7. Quantize probs (recompute exp2) -> pq ----
        #pragma unroll
        for (int rt = 0; rt < 2; ++rt) {
            const int koff = wv * 32 + rt * 16 + g * 4;
            {
                const unsigned int w0 = scA[2 * rt], w1 = scA[2 * rt + 1];
                int q0 = (int)rintf(fexp2((float)((int)(short)(w0 & 0xffffu) - gmA) * C) * qsA);
                int q1 = (int)rintf(fexp2((float)(((int)w0 >> 16) - gmA) * C) * qsA);
                int q2 = (int)rintf(fexp2((float)((int)(short)(w1 & 0xffffu) - gmA) * C) * qsA);
                int q3 = (int)rintf(fexp2((float)(((int)w1 >> 16) - gmA) * C) * qsA);
                q0 = q0 > 127 ? 127 : q0;
                q1 = q1 > 127 ? 127 : q1;
                q2 = q2 > 127 ? 127 : q2;
                q3 = q3 > 127 ? 127 : q3;
                *reinterpret_cast<unsigned int*>(
                    pq + c * 256 + (koff ^ (c << 4))) =
                    (unsigned int)(q0 | (q1 << 8) | (q2 << 16) | (q3 << 24));
            }
            {
                const unsigned int w0 = scB[2 * rt], w1 = scB[2 * rt + 1];
                int q0 = (int)rintf(fexp2((float)((int)(short)(w0 & 0xffffu) - gmB) * C) * qsB);
                int q1 = (int)rintf(fexp2((float)(((int)w0 >> 16) - gmB) * C) * qsB);
                int q2 = (int)rintf(fexp2((float)((int)(short)(w1 & 0xffffu) - gmB) * C) * qsB);
                int q3 = (int)rintf(fexp2((float)(((int)w1 >> 16) - gmB) * C) * qsB);
                q0 = q0 > 127 ? 127 : q0;
                q1 = q1 > 127 ? 127 : q1;
                q2 = q2 > 127 ? 127 : q2;
                q3 = q3 > 127 ? 127 : q3;
                *reinterpret_cast<unsigned int*>(
                    pq + (16 + c) * 256 + (koff ^ (c << 4))) =
                    (unsigned int)(q0 | (q1 << 8) | (q2 << 16) | (q3 << 24));
            }
        }
        __syncthreads();   // P: pq complete

        // ---- 8. GEMM2: B from pq, A resident; direct stores ----
        int4v b2[2][4];
        #pragma unroll
        for (int t2 = 0; t2 < 2; ++t2)
            #pragma unroll
            for (int kk = 0; kk < 4; ++kk)
                b2[t2][kk] = *reinterpret_cast<const int4v*>(
                    pq + (t2 * 16 + c) * 256 + ((kk * 64 + g * 16) ^ (c << 4)));

        #pragma unroll
        for (int rt = 0; rt < 2; ++rt) {
            int4v accA = {0, 0, 0, 0}, accB = {0, 0, 0, 0};
            #pragma unroll
            for (int kk = 0; kk < 4; ++kk) {
                accA = __builtin_amdgcn_mfma_i32_16x16x64_i8(a2f[rt][kk], b2[0][kk], accA, 0, 0, 0);
                accB = __builtin_amdgcn_mfma_i32_16x16x64_i8(a2f[rt][kk], b2[1][kk], accB, 0, 0, 0);
            }
            #pragma unroll
            for (int r = 0; r < 4; ++r) {
                const size_t rowoff =
                    (size_t)(wv * 32 + rt * 16 + g * 4 + r) * N_DIM + col0;
                out[rowoff + c]      = clamp16(accA[r]);
                out[rowoff + 16 + c] = clamp16(accB[r]);
            }
        }
    }
}

extern "C" void kernel_launch(void* const* d_in, const int* in_sizes, int n_in,
                              void* d_out, int out_size, void* d_ws, size_t ws_size,
                              hipStream_t stream) {
    const float* x  = (const float*)d_in[0];
    const float* w1 = (const float*)d_in[1];
    const float* w2 = (const float*)d_in[2];
    int* out = (int*)d_out;

    unsigned char* w1q = (unsigned char*)d_ws;
    unsigned char* w2q = w1q + 65536;

    quant_weights<<<128, 256, 0, stream>>>(w1, w2, w1q, w2q);
    qdq_main<<<256, 512, 0, stream>>>(x, w1q, w2q, out);
}